// Round 3
// baseline (2427.032 us; speedup 1.0000x reference)
//
#include <hip/hip_runtime.h>
#include <hip/hip_bf16.h>
#include <math.h>

#define L_SEQ 6464
#define DM 64
#define DI 128
#define DS 16
#define CHUNK 101
#define NCH 64
#define TSTR 108   // padded LDS stride (16B-aligned, 2-way max bank alias)

// ---------------- prologue: concat + pos, then @W_fcc + b_fcc ----------------
__global__ void k_embed(const float* __restrict__ DNA, const float* __restrict__ CpG,
                        const float* __restrict__ cell, const float* __restrict__ pos,
                        const float* __restrict__ Wfcc, const float* __restrict__ bfcc,
                        float* __restrict__ x0) {
    int l = blockIdx.x;
    int j = threadIdx.x;  // 64
    __shared__ float in64[64];
    float v;
    if (j < 16)       v = CpG[l * 16 + j];
    else if (j < 32)  v = cell[l * 16 + (j - 16)];
    else              v = DNA[l * 32 + (j - 32)];
    v += pos[l * 64 + j];
    in64[j] = v;
    __syncthreads();
    float acc = bfcc[j];
    for (int i = 0; i < 64; i++) acc += in64[i] * Wfcc[i * 64 + j];
    x0[(size_t)l * 64 + j] = acc;
}

// ---------------- xz = x @ W_in  (L x 64 @ 64 x 256) ----------------
__global__ void k_gemm_in(const float* __restrict__ x, const float* __restrict__ Win,
                          float* __restrict__ xz) {
    int l = blockIdx.x;
    int j = threadIdx.x;  // 256
    __shared__ float xr[64];
    if (j < 64) xr[j] = x[(size_t)l * 64 + j];
    __syncthreads();
    float acc = 0.f;
    for (int i = 0; i < 64; i++) acc += xr[i] * Win[i * 256 + j];
    xz[(size_t)l * 256 + j] = acc;
}

// ---------------- depthwise causal conv + silu, both directions ----------------
__global__ void k_conv(const float* __restrict__ xz, const float* __restrict__ convw,
                       const float* __restrict__ convb, float* __restrict__ xc) {
    int idx = blockIdx.x * blockDim.x + threadIdx.x;
    if (idx >= 2 * L_SEQ * DI) return;
    int d = idx & 127;
    int l = (idx >> 7) % L_SEQ;
    int dir = idx / (L_SEQ * DI);
    float acc = convb[d];
    if (dir == 0) {
        for (int k = 0; k < 4; k++) {
            int r = l - 3 + k;
            if (r >= 0) acc += convw[d * 4 + k] * xz[(size_t)r * 256 + d];
        }
    } else {
        for (int k = 0; k < 4; k++) {
            int r = l + 3 - k;
            if (r < L_SEQ) acc += convw[d * 4 + k] * xz[(size_t)r * 256 + d];
        }
    }
    xc[idx] = acc / (1.f + expf(-acc));  // silu
}

// ---------------- xdbl = xc @ W_xp ; dt = softplus(xdbl[:,:4]@W_dt + b_dt) ----------------
__global__ void k_xp_dt(const float* __restrict__ xc, const float* __restrict__ Wxp,
                        const float* __restrict__ Wdt, const float* __restrict__ bdt,
                        float* __restrict__ dt, float* __restrict__ BC) {
    int blk = blockIdx.x;             // 2*L
    int dir = blk / L_SEQ;
    int l = blk % L_SEQ;
    int t = threadIdx.x;              // 128
    const float* xcrow = xc + (size_t)(dir * L_SEQ + l) * DI;
    __shared__ float xr[128];
    __shared__ float xd[36];
    xr[t] = xcrow[t];
    __syncthreads();
    if (t < 36) {
        float acc = 0.f;
        for (int i = 0; i < 128; i++) acc += xr[i] * Wxp[i * 36 + t];
        xd[t] = acc;
    }
    __syncthreads();
    float pre = bdt[t];
    for (int r = 0; r < 4; r++) pre += xd[r] * Wdt[r * 128 + t];
    float dtv = (pre > 20.f) ? pre : log1pf(expf(pre));
    dt[(size_t)(dir * L_SEQ + l) * DI + t] = dtv;
    if (t < 32) BC[(size_t)(dir * L_SEQ + l) * 32 + t] = xd[4 + t];
}

// ---------------- fused selective scan: stage->local scan->lookback->replay ----------------
template<int CTRL>
__device__ __forceinline__ float ror16f(float v) {
    return __int_as_float(__builtin_amdgcn_update_dpp(0, __float_as_int(v), CTRL, 0xf, 0xf, true));
}

__global__ void k_zero(int* __restrict__ p, int n) {
    int i = blockIdx.x * 256 + threadIdx.x;
    if (i < n) p[i] = 0;
}

__global__ void __launch_bounds__(256) k_scan_fused(
        const float* __restrict__ dt, const float* __restrict__ xc,
        const float* __restrict__ BC, const float* __restrict__ xz,
        const float* __restrict__ Alog, const float* __restrict__ Dres,
        float* __restrict__ cA, float* __restrict__ cB,
        int* __restrict__ flags, int* __restrict__ counter,
        float* __restrict__ g) {
    __shared__ __align__(16) float s_dt[16 * TSTR];
    __shared__ __align__(16) float s_xc[16 * TSTR];
    __shared__ __align__(16) float s_B [16 * TSTR];
    __shared__ __align__(16) float s_C [16 * TSTR];
    __shared__ __align__(16) float s_z [16 * TSTR];
    __shared__ int s_ticket;
    int tid = threadIdx.x;
    if (tid == 0) s_ticket = atomicAdd(counter, 1);
    __syncthreads();
    int tk  = s_ticket;
    int c   = tk >> 4;          // chunk index: low tickets -> low chunks (deadlock-free)
    int dir = (tk >> 3) & 1;
    int bxd = tk & 7;           // d-group
    int d0  = bxd * 16;
    int s   = tid & 15;
    int dl  = tid >> 4;
    const float* dtp = dt + (size_t)dir * L_SEQ * DI;
    const float* xcp = xc + (size_t)dir * L_SEQ * DI;
    const float* bcp = BC + (size_t)dir * L_SEQ * 32;
    float* gp = g + (size_t)dir * L_SEQ * DI;
    int t0 = c * CHUNK;

    // ---- stage chunk into LDS (transposed layouts), coalesced global reads ----
    for (int i = tid; i < CHUNK * 16; i += 256) {
        int tl = i >> 4, dd = i & 15;
        int row = dir ? (L_SEQ - 1 - (t0 + tl)) : (t0 + tl);
        s_dt[dd * TSTR + tl] = dtp[(size_t)row * DI + d0 + dd];
        s_xc[dd * TSTR + tl] = xcp[(size_t)row * DI + d0 + dd];
        s_z [dd * TSTR + tl] = xz [(size_t)row * 256 + 128 + d0 + dd];
    }
    for (int i = tid; i < CHUNK * 32; i += 256) {
        int tl = i >> 5, w = i & 31;
        int row = dir ? (L_SEQ - 1 - (t0 + tl)) : (t0 + tl);
        float v = bcp[(size_t)row * 32 + w];
        if (w < 16) s_B[w * TSTR + tl] = v;
        else        s_C[(w - 16) * TSTR + tl] = v;
    }
    __syncthreads();

    float A = -expf(Alog[(d0 + dl) * 16 + s]);
    const int tb = dl * TSTR;
    const int sb = s * TSTR;

    // ---- phase A: local scan (a_prod, h_end) ----
    float h = 0.f, ap = 1.f;
    {
        int tl = 0;
        for (int u = 0; u < 25; u++, tl += 4) {
            float4 dq = *(const float4*)&s_dt[tb + tl];
            float4 xq = *(const float4*)&s_xc[tb + tl];
            float4 bq = *(const float4*)&s_B [sb + tl];
            float a;
            a = __expf(dq.x * A); h = fmaf(a, h, dq.x * xq.x * bq.x); ap *= a;
            a = __expf(dq.y * A); h = fmaf(a, h, dq.y * xq.y * bq.y); ap *= a;
            a = __expf(dq.z * A); h = fmaf(a, h, dq.z * xq.z * bq.z); ap *= a;
            a = __expf(dq.w * A); h = fmaf(a, h, dq.w * xq.w * bq.w); ap *= a;
        }
        float dv = s_dt[tb + 100], xv = s_xc[tb + 100], bv = s_B[sb + 100];
        float a = __expf(dv * A); h = fmaf(a, h, dv * xv * bv); ap *= a;
    }

    // ---- publish (a_prod, h_end), release flag ----
    size_t o = (((size_t)dir * NCH + c) << 11) + (size_t)bxd * 256 + tid;
    __hip_atomic_store(&cA[o], ap, __ATOMIC_RELAXED, __HIP_MEMORY_SCOPE_AGENT);
    __hip_atomic_store(&cB[o], h, __ATOMIC_RELAXED, __HIP_MEMORY_SCOPE_AGENT);
    __threadfence();
    __syncthreads();
    int fbase = (dir * 8 + bxd) * 64;
    if (tid == 0)
        __hip_atomic_store(&flags[fbase + c], 1, __ATOMIC_RELEASE, __HIP_MEMORY_SCOPE_AGENT);

    // ---- lookback: combine all predecessor chunk carries ----
    float carry = 0.f;
    if (c > 0) {
        for (int cc = 0; cc < c; cc++) {
            while (__hip_atomic_load(&flags[fbase + cc], __ATOMIC_RELAXED,
                                     __HIP_MEMORY_SCOPE_AGENT) == 0) {
                __builtin_amdgcn_s_sleep(1);
            }
        }
        __threadfence();   // acquire: order data reads after flag observations
        int cc = 0;
        while (cc < c) {
            int n = (c - cc < 8) ? (c - cc) : 8;
            float av[8], bv[8];
            for (int j = 0; j < n; j++) {
                size_t oo = (((size_t)dir * NCH + (cc + j)) << 11) + (size_t)bxd * 256 + tid;
                av[j] = __hip_atomic_load(&cA[oo], __ATOMIC_RELAXED, __HIP_MEMORY_SCOPE_AGENT);
                bv[j] = __hip_atomic_load(&cB[oo], __ATOMIC_RELAXED, __HIP_MEMORY_SCOPE_AGENT);
            }
            for (int j = 0; j < n; j++) carry = fmaf(av[j], carry, bv[j]);
            cc += n;
        }
    }

    // ---- phase B: replay with carry-in, contract with C, write g ----
    float Dv = Dres[d0 + dl];
    h = carry;
    {
        int tl = 0;
        for (int u = 0; u < 25; u++, tl += 4) {
            float4 dq = *(const float4*)&s_dt[tb + tl];
            float4 xq = *(const float4*)&s_xc[tb + tl];
            float4 bq = *(const float4*)&s_B [sb + tl];
            float4 cq = *(const float4*)&s_C [sb + tl];
            float4 zq = *(const float4*)&s_z [tb + tl];
            #pragma unroll
            for (int k = 0; k < 4; k++) {
                float dv = (k == 0) ? dq.x : (k == 1) ? dq.y : (k == 2) ? dq.z : dq.w;
                float xv = (k == 0) ? xq.x : (k == 1) ? xq.y : (k == 2) ? xq.z : xq.w;
                float bv = (k == 0) ? bq.x : (k == 1) ? bq.y : (k == 2) ? bq.z : bq.w;
                float cv = (k == 0) ? cq.x : (k == 1) ? cq.y : (k == 2) ? cq.z : cq.w;
                float zv = (k == 0) ? zq.x : (k == 1) ? zq.y : (k == 2) ? zq.z : zq.w;
                float a = __expf(dv * A);
                h = fmaf(a, h, dv * xv * bv);
                float val = h * cv;
                val += ror16f<0x121>(val);
                val += ror16f<0x122>(val);
                val += ror16f<0x124>(val);
                val += ror16f<0x128>(val);
                if (s == 0) {
                    float y = val + xv * Dv;
                    float sz = zv / (1.f + __expf(-zv));
                    int row = dir ? (L_SEQ - 1 - (t0 + tl + k)) : (t0 + tl + k);
                    gp[(size_t)row * DI + d0 + dl] = y * sz;
                }
            }
        }
        // tail tl = 100
        float dv = s_dt[tb + 100], xv = s_xc[tb + 100];
        float bv = s_B[sb + 100],  cv = s_C[sb + 100], zv = s_z[tb + 100];
        float a = __expf(dv * A);
        h = fmaf(a, h, dv * xv * bv);
        float val = h * cv;
        val += ror16f<0x121>(val);
        val += ror16f<0x122>(val);
        val += ror16f<0x124>(val);
        val += ror16f<0x128>(val);
        if (s == 0) {
            float y = val + xv * Dv;
            float sz = zv / (1.f + __expf(-zv));
            int row = dir ? (L_SEQ - 1 - (t0 + 100)) : (t0 + 100);
            gp[(size_t)row * DI + d0 + dl] = y * sz;
        }
    }
}

// ---------------- out-GEMM + residual + layernorm + transpose-permute ----------------
__global__ void k_outln(const float* __restrict__ x, const float* __restrict__ g,
                        const float* __restrict__ Wout, const float* __restrict__ lng,
                        const float* __restrict__ lnb, float* __restrict__ xnext,
                        int permMode) {
    int l = blockIdx.x;
    int j = threadIdx.x;  // 64 (one wave)
    __shared__ float gs[128];
    gs[j] = 0.5f * (g[(size_t)l * 128 + j] + g[(size_t)(L_SEQ + l) * 128 + j]);
    gs[j + 64] = 0.5f * (g[(size_t)l * 128 + 64 + j] + g[(size_t)(L_SEQ + l) * 128 + 64 + j]);
    __syncthreads();
    float acc = x[(size_t)l * 64 + j];
    for (int i = 0; i < 128; i++) acc += gs[i] * Wout[i * 64 + j];
    float m = acc;
    for (int o = 32; o >= 1; o >>= 1) m += __shfl_xor(m, o);
    m *= (1.f / 64.f);
    float dv = acc - m;
    float v = dv * dv;
    for (int o = 32; o >= 1; o >>= 1) v += __shfl_xor(v, o);
    v *= (1.f / 64.f);
    float out = dv * rsqrtf(v + 1e-5f) * lng[j] + lnb[j];
    int l2;
    if (permMode == 0) l2 = (l % 64) * 101 + (l / 64);   // (s,c)->(c,s)
    else               l2 = (l % 101) * 64 + (l / 101);  // (c,s)->(s,c)
    xnext[(size_t)l2 * 64 + j] = out;
}

// ---------------- epilogue ----------------
__global__ void k_epilogue(const float* __restrict__ x, const float* __restrict__ Wfc,
                           const float* __restrict__ bfc, const float* __restrict__ ytrue,
                           const int* __restrict__ halfwin, const int* __restrict__ rows,
                           float* __restrict__ out) {
    int k = threadIdx.x;  // 64
    int hw = halfwin[0];
    int c = rows[k];
    const float* xr = x + ((size_t)hw * 64 + c) * 64;
    float acc = bfc[0];
    for (int i = 0; i < 64; i++) acc += xr[i] * Wfc[i];
    float s = 1.f / (1.f + expf(-acc));
    float r = 1.f - fabsf(ytrue[k] - s);
    out[k] = r;
}

extern "C" void kernel_launch(void* const* d_in, const int* in_sizes, int n_in,
                              void* d_out, int out_size, void* d_ws, size_t ws_size,
                              hipStream_t stream) {
    const float* DNA   = (const float*)d_in[0];
    const float* CpG   = (const float*)d_in[1];
    const float* cel   = (const float*)d_in[2];
    const float* pos   = (const float*)d_in[3];
    const float* ytrue = (const float*)d_in[4];
    const float* Wfcc  = (const float*)d_in[5];
    const float* bfcc  = (const float*)d_in[6];
    const float* Win   = (const float*)d_in[7];
    const float* convw = (const float*)d_in[8];
    const float* convb = (const float*)d_in[9];
    const float* Wxp   = (const float*)d_in[10];
    const float* Wdt   = (const float*)d_in[11];
    const float* bdt   = (const float*)d_in[12];
    const float* Alog  = (const float*)d_in[13];
    const float* Dres  = (const float*)d_in[14];
    const float* Wout  = (const float*)d_in[15];
    const float* lng   = (const float*)d_in[16];
    const float* lnb   = (const float*)d_in[17];
    const float* Wfc   = (const float*)d_in[18];
    const float* bfc   = (const float*)d_in[19];
    const int* halfwin = (const int*)d_in[20];
    const int* rows    = (const int*)d_in[21];

    float* ws = (float*)d_ws;
    size_t off = 0;
    float* x0 = ws + off; off += (size_t)L_SEQ * 64;
    float* x1 = ws + off; off += (size_t)L_SEQ * 64;
    float* xz = ws + off; off += (size_t)L_SEQ * 256;
    float* xc = ws + off; off += (size_t)2 * L_SEQ * 128;
    float* dt = ws + off; off += (size_t)2 * L_SEQ * 128;
    float* BC = ws + off; off += (size_t)2 * L_SEQ * 32;
    float* g  = ws + off; off += (size_t)2 * L_SEQ * 128;
    float* cA = ws + off; off += (size_t)2 * NCH * 2048;
    float* cB = ws + off; off += (size_t)2 * NCH * 2048;
    int* flags    = (int*)(ws + off);   // 8 sub-blocks x 1024 flags
    int* counters = flags + 8 * 1024;   // 8 ticket counters

    k_zero<<<(8 * 1024 + 8 + 255) / 256, 256, 0, stream>>>(flags, 8 * 1024 + 8);
    k_embed<<<L_SEQ, 64, 0, stream>>>(DNA, CpG, cel, pos, Wfcc, bfcc, x0);

    float* xcur = x0;
    float* xnxt = x1;
    for (int sb = 0; sb < 8; sb++) {
        k_gemm_in<<<L_SEQ, 256, 0, stream>>>(xcur, Win, xz);
        k_conv<<<(2 * L_SEQ * DI + 255) / 256, 256, 0, stream>>>(xz, convw, convb, xc);
        k_xp_dt<<<2 * L_SEQ, 128, 0, stream>>>(xc, Wxp, Wdt, bdt, dt, BC);
        k_scan_fused<<<1024, 256, 0, stream>>>(dt, xc, BC, xz, Alog, Dres, cA, cB,
                                               flags + sb * 1024, counters + sb, g);
        k_outln<<<L_SEQ, 64, 0, stream>>>(xcur, g, Wout, lng, lnb, xnxt, (sb % 2 == 0) ? 0 : 1);
        float* tmp = xcur; xcur = xnxt; xnxt = tmp;
    }

    k_epilogue<<<1, 64, 0, stream>>>(xcur, Wfc, bfc, ytrue, halfwin, rows, (float*)d_out);
}

// Round 4
// 980.207 us; speedup vs baseline: 2.4760x; 2.4760x over previous
//
#include <hip/hip_runtime.h>
#include <hip/hip_bf16.h>
#include <math.h>

#define L_SEQ 6464
#define DM 64
#define DI 128
#define DS 16
#define CHUNK 101
#define NCH 64
#define TSTR 108   // padded LDS stride: 108*4B = 27*16B (aligned); 12s mod 32 -> 2-way alias only (free)

// ---------------- prologue: concat + pos, then @W_fcc + b_fcc ----------------
__global__ void k_embed(const float* __restrict__ DNA, const float* __restrict__ CpG,
                        const float* __restrict__ cell, const float* __restrict__ pos,
                        const float* __restrict__ Wfcc, const float* __restrict__ bfcc,
                        float* __restrict__ x0) {
    int l = blockIdx.x;
    int j = threadIdx.x;  // 64
    __shared__ float in64[64];
    float v;
    if (j < 16)       v = CpG[l * 16 + j];
    else if (j < 32)  v = cell[l * 16 + (j - 16)];
    else              v = DNA[l * 32 + (j - 32)];
    v += pos[l * 64 + j];
    in64[j] = v;
    __syncthreads();
    float acc = bfcc[j];
    for (int i = 0; i < 64; i++) acc += in64[i] * Wfcc[i * 64 + j];
    x0[(size_t)l * 64 + j] = acc;
}

// ---------------- xz = x @ W_in  (L x 64 @ 64 x 256) ----------------
__global__ void k_gemm_in(const float* __restrict__ x, const float* __restrict__ Win,
                          float* __restrict__ xz) {
    int l = blockIdx.x;
    int j = threadIdx.x;  // 256
    __shared__ float xr[64];
    if (j < 64) xr[j] = x[(size_t)l * 64 + j];
    __syncthreads();
    float acc = 0.f;
    for (int i = 0; i < 64; i++) acc += xr[i] * Win[i * 256 + j];
    xz[(size_t)l * 256 + j] = acc;
}

// ---------------- depthwise causal conv + silu, both directions ----------------
__global__ void k_conv(const float* __restrict__ xz, const float* __restrict__ convw,
                       const float* __restrict__ convb, float* __restrict__ xc) {
    int idx = blockIdx.x * blockDim.x + threadIdx.x;
    if (idx >= 2 * L_SEQ * DI) return;
    int d = idx & 127;
    int l = (idx >> 7) % L_SEQ;
    int dir = idx / (L_SEQ * DI);
    float acc = convb[d];
    if (dir == 0) {
        for (int k = 0; k < 4; k++) {
            int r = l - 3 + k;
            if (r >= 0) acc += convw[d * 4 + k] * xz[(size_t)r * 256 + d];
        }
    } else {
        for (int k = 0; k < 4; k++) {
            int r = l + 3 - k;
            if (r < L_SEQ) acc += convw[d * 4 + k] * xz[(size_t)r * 256 + d];
        }
    }
    xc[idx] = acc / (1.f + expf(-acc));  // silu
}

// ---------------- xdbl = xc @ W_xp ; dt = softplus(xdbl[:,:4]@W_dt + b_dt) ----------------
__global__ void k_xp_dt(const float* __restrict__ xc, const float* __restrict__ Wxp,
                        const float* __restrict__ Wdt, const float* __restrict__ bdt,
                        float* __restrict__ dt, float* __restrict__ BC) {
    int blk = blockIdx.x;             // 2*L
    int dir = blk / L_SEQ;
    int l = blk % L_SEQ;
    int t = threadIdx.x;              // 128
    const float* xcrow = xc + (size_t)(dir * L_SEQ + l) * DI;
    __shared__ float xr[128];
    __shared__ float xd[36];
    xr[t] = xcrow[t];
    __syncthreads();
    if (t < 36) {
        float acc = 0.f;
        for (int i = 0; i < 128; i++) acc += xr[i] * Wxp[i * 36 + t];
        xd[t] = acc;
    }
    __syncthreads();
    float pre = bdt[t];
    for (int r = 0; r < 4; r++) pre += xd[r] * Wdt[r * 128 + t];
    float dtv = (pre > 20.f) ? pre : log1pf(expf(pre));
    dt[(size_t)(dir * L_SEQ + l) * DI + t] = dtv;
    if (t < 32) BC[(size_t)(dir * L_SEQ + l) * 32 + t] = xd[4 + t];
}

// ---------------- DPP 16-lane row rotate ----------------
template<int CTRL>
__device__ __forceinline__ float ror16f(float v) {
    return __int_as_float(__builtin_amdgcn_update_dpp(0, __float_as_int(v), CTRL, 0xf, 0xf, true));
}

// ---------------- scan pass 1: staged per-chunk (a_prod, h_end) ----------------
__global__ void __launch_bounds__(256) k_scan1s(
        const float* __restrict__ dt, const float* __restrict__ xc,
        const float* __restrict__ BC, const float* __restrict__ Alog,
        float* __restrict__ cA, float* __restrict__ cB) {
    __shared__ __align__(16) float s_dt[16 * TSTR];
    __shared__ __align__(16) float s_xc[16 * TSTR];
    __shared__ __align__(16) float s_B [16 * TSTR];
    int bxd = blockIdx.x;   // d-group (8)
    int c   = blockIdx.y;   // chunk (64)
    int dir = blockIdx.z;   // 2
    int tid = threadIdx.x;
    int s = tid & 15, dl = tid >> 4;
    int d0 = bxd * 16;
    const float* dtp = dt + (size_t)dir * L_SEQ * DI;
    const float* xcp = xc + (size_t)dir * L_SEQ * DI;
    const float* bcp = BC + (size_t)dir * L_SEQ * 32;
    int t0 = c * CHUNK;
    for (int i = tid; i < CHUNK * 16; i += 256) {
        int tl = i >> 4, dd = i & 15;
        int row = dir ? (L_SEQ - 1 - (t0 + tl)) : (t0 + tl);
        s_dt[dd * TSTR + tl] = dtp[(size_t)row * DI + d0 + dd];
        s_xc[dd * TSTR + tl] = xcp[(size_t)row * DI + d0 + dd];
        s_B [dd * TSTR + tl] = bcp[(size_t)row * 32 + dd];
    }
    __syncthreads();
    float A = -expf(Alog[d0 * 16 + tid]);
    const int tb = dl * TSTR;
    const int sbb = s * TSTR;
    float h = 0.f, ap = 1.f;
    int tl = 0;
    for (int u = 0; u < 25; u++, tl += 4) {
        float4 dq = *(const float4*)&s_dt[tb + tl];
        float4 xq = *(const float4*)&s_xc[tb + tl];
        float4 bq = *(const float4*)&s_B [sbb + tl];
        float a;
        a = __expf(dq.x * A); h = fmaf(a, h, dq.x * xq.x * bq.x); ap *= a;
        a = __expf(dq.y * A); h = fmaf(a, h, dq.y * xq.y * bq.y); ap *= a;
        a = __expf(dq.z * A); h = fmaf(a, h, dq.z * xq.z * bq.z); ap *= a;
        a = __expf(dq.w * A); h = fmaf(a, h, dq.w * xq.w * bq.w); ap *= a;
    }
    {
        float dv = s_dt[tb + 100], xv = s_xc[tb + 100], bv = s_B[sbb + 100];
        float a = __expf(dv * A); h = fmaf(a, h, dv * xv * bv); ap *= a;
    }
    size_t o = (((size_t)dir * NCH + c) << 11) + (size_t)bxd * 256 + tid;
    cA[o] = ap;
    cB[o] = h;
}

// ---------------- scan pass 2: lookback (plain loads, stream-ordered) + replay ----------------
__global__ void __launch_bounds__(256) k_scan3s(
        const float* __restrict__ dt, const float* __restrict__ xc,
        const float* __restrict__ BC, const float* __restrict__ Alog,
        const float* __restrict__ Dres, const float* __restrict__ cA,
        const float* __restrict__ cB, float* __restrict__ y) {
    __shared__ __align__(16) float s_dt[16 * TSTR];
    __shared__ __align__(16) float s_xc[16 * TSTR];
    __shared__ __align__(16) float s_B [16 * TSTR];
    __shared__ __align__(16) float s_C [16 * TSTR];
    __shared__ __align__(16) float s_y [16 * TSTR];
    int bxd = blockIdx.x;
    int c   = blockIdx.y;
    int dir = blockIdx.z;
    int tid = threadIdx.x;
    int s = tid & 15, dl = tid >> 4;
    int d0 = bxd * 16;
    const float* dtp = dt + (size_t)dir * L_SEQ * DI;
    const float* xcp = xc + (size_t)dir * L_SEQ * DI;
    const float* bcp = BC + (size_t)dir * L_SEQ * 32;
    float* yp = y + (size_t)dir * L_SEQ * DI;
    int t0 = c * CHUNK;
    for (int i = tid; i < CHUNK * 16; i += 256) {
        int tl = i >> 4, dd = i & 15;
        int row = dir ? (L_SEQ - 1 - (t0 + tl)) : (t0 + tl);
        s_dt[dd * TSTR + tl] = dtp[(size_t)row * DI + d0 + dd];
        s_xc[dd * TSTR + tl] = xcp[(size_t)row * DI + d0 + dd];
    }
    for (int i = tid; i < CHUNK * 32; i += 256) {
        int tl = i >> 5, w = i & 31;
        int row = dir ? (L_SEQ - 1 - (t0 + tl)) : (t0 + tl);
        float v = bcp[(size_t)row * 32 + w];
        if (w < 16) s_B[w * TSTR + tl] = v;
        else        s_C[(w - 16) * TSTR + tl] = v;
    }

    // lookback: fold predecessor carries (produced by k_scan1s, stream-ordered)
    float carry = 0.f;
    int cc = 0;
    while (cc < c) {
        int n = (c - cc < 8) ? (c - cc) : 8;
        float av[8], bv[8];
        for (int j = 0; j < n; j++) {
            size_t oo = (((size_t)dir * NCH + (cc + j)) << 11) + (size_t)bxd * 256 + tid;
            av[j] = cA[oo];
            bv[j] = cB[oo];
        }
        for (int j = 0; j < n; j++) carry = fmaf(av[j], carry, bv[j]);
        cc += n;
    }
    __syncthreads();

    float A = -expf(Alog[d0 * 16 + tid]);
    float Dv = Dres[d0 + dl];
    const int tb = dl * TSTR;
    const int sbb = s * TSTR;
    float h = carry;
    int tl = 0;
    for (int u = 0; u < 25; u++, tl += 4) {
        float4 dq = *(const float4*)&s_dt[tb + tl];
        float4 xq = *(const float4*)&s_xc[tb + tl];
        float4 bq = *(const float4*)&s_B [sbb + tl];
        float4 cq = *(const float4*)&s_C [sbb + tl];
        #pragma unroll
        for (int k = 0; k < 4; k++) {
            float dv = (k == 0) ? dq.x : (k == 1) ? dq.y : (k == 2) ? dq.z : dq.w;
            float xv = (k == 0) ? xq.x : (k == 1) ? xq.y : (k == 2) ? xq.z : xq.w;
            float bv = (k == 0) ? bq.x : (k == 1) ? bq.y : (k == 2) ? bq.z : bq.w;
            float cv = (k == 0) ? cq.x : (k == 1) ? cq.y : (k == 2) ? cq.z : cq.w;
            float a = __expf(dv * A);
            h = fmaf(a, h, dv * xv * bv);
            float val = h * cv;
            val += ror16f<0x121>(val);
            val += ror16f<0x122>(val);
            val += ror16f<0x124>(val);
            val += ror16f<0x128>(val);
            if (s == 0) s_y[tb + tl + k] = val + xv * Dv;
        }
    }
    {
        float dv = s_dt[tb + 100], xv = s_xc[tb + 100];
        float bv = s_B[sbb + 100], cv = s_C[sbb + 100];
        float a = __expf(dv * A);
        h = fmaf(a, h, dv * xv * bv);
        float val = h * cv;
        val += ror16f<0x121>(val);
        val += ror16f<0x122>(val);
        val += ror16f<0x124>(val);
        val += ror16f<0x128>(val);
        if (s == 0) s_y[tb + 100] = val + xv * Dv;
    }
    __syncthreads();
    for (int i = tid; i < CHUNK * 16; i += 256) {
        int tl2 = i >> 4, dd = i & 15;
        int row = dir ? (L_SEQ - 1 - (t0 + tl2)) : (t0 + tl2);
        yp[(size_t)row * DI + d0 + dd] = s_y[dd * TSTR + tl2];
    }
}

// ---------------- out-GEMM + silu(z) gate + residual + layernorm + permute ----------------
__global__ void k_outln(const float* __restrict__ x, const float* __restrict__ y,
                        const float* __restrict__ xz, const float* __restrict__ Wout,
                        const float* __restrict__ lng, const float* __restrict__ lnb,
                        float* __restrict__ xnext, int permMode) {
    int l = blockIdx.x;
    int j = threadIdx.x;  // 64 (one wave)
    __shared__ float gs[128];
    float z1 = xz[(size_t)l * 256 + 128 + j];
    float z2 = xz[(size_t)l * 256 + 192 + j];
    float sz1 = z1 / (1.f + expf(-z1));
    float sz2 = z2 / (1.f + expf(-z2));
    gs[j]      = 0.5f * (y[(size_t)l * 128 + j] + y[(size_t)(L_SEQ + l) * 128 + j]) * sz1;
    gs[j + 64] = 0.5f * (y[(size_t)l * 128 + 64 + j] + y[(size_t)(L_SEQ + l) * 128 + 64 + j]) * sz2;
    __syncthreads();
    float acc = x[(size_t)l * 64 + j];
    for (int i = 0; i < 128; i++) acc += gs[i] * Wout[i * 64 + j];
    float m = acc;
    for (int o = 32; o >= 1; o >>= 1) m += __shfl_xor(m, o);
    m *= (1.f / 64.f);
    float dv = acc - m;
    float v = dv * dv;
    for (int o = 32; o >= 1; o >>= 1) v += __shfl_xor(v, o);
    v *= (1.f / 64.f);
    float out = dv * rsqrtf(v + 1e-5f) * lng[j] + lnb[j];
    int l2;
    if (permMode == 0) l2 = (l % 64) * 101 + (l / 64);   // (s,c)->(c,s)
    else               l2 = (l % 101) * 64 + (l / 101);  // (c,s)->(s,c)
    xnext[(size_t)l2 * 64 + j] = out;
}

// ---------------- epilogue ----------------
__global__ void k_epilogue(const float* __restrict__ x, const float* __restrict__ Wfc,
                           const float* __restrict__ bfc, const float* __restrict__ ytrue,
                           const int* __restrict__ halfwin, const int* __restrict__ rows,
                           float* __restrict__ out) {
    int k = threadIdx.x;  // 64
    int hw = halfwin[0];
    int c = rows[k];
    const float* xr = x + ((size_t)hw * 64 + c) * 64;
    float acc = bfc[0];
    for (int i = 0; i < 64; i++) acc += xr[i] * Wfc[i];
    float s = 1.f / (1.f + expf(-acc));
    float r = 1.f - fabsf(ytrue[k] - s);
    out[k] = r;
}

extern "C" void kernel_launch(void* const* d_in, const int* in_sizes, int n_in,
                              void* d_out, int out_size, void* d_ws, size_t ws_size,
                              hipStream_t stream) {
    const float* DNA   = (const float*)d_in[0];
    const float* CpG   = (const float*)d_in[1];
    const float* cel   = (const float*)d_in[2];
    const float* pos   = (const float*)d_in[3];
    const float* ytrue = (const float*)d_in[4];
    const float* Wfcc  = (const float*)d_in[5];
    const float* bfcc  = (const float*)d_in[6];
    const float* Win   = (const float*)d_in[7];
    const float* convw = (const float*)d_in[8];
    const float* convb = (const float*)d_in[9];
    const float* Wxp   = (const float*)d_in[10];
    const float* Wdt   = (const float*)d_in[11];
    const float* bdt   = (const float*)d_in[12];
    const float* Alog  = (const float*)d_in[13];
    const float* Dres  = (const float*)d_in[14];
    const float* Wout  = (const float*)d_in[15];
    const float* lng   = (const float*)d_in[16];
    const float* lnb   = (const float*)d_in[17];
    const float* Wfc   = (const float*)d_in[18];
    const float* bfc   = (const float*)d_in[19];
    const int* halfwin = (const int*)d_in[20];
    const int* rows    = (const int*)d_in[21];

    float* ws = (float*)d_ws;
    size_t off = 0;
    float* x0 = ws + off; off += (size_t)L_SEQ * 64;
    float* x1 = ws + off; off += (size_t)L_SEQ * 64;
    float* xz = ws + off; off += (size_t)L_SEQ * 256;
    float* xc = ws + off; off += (size_t)2 * L_SEQ * 128;
    float* dt = ws + off; off += (size_t)2 * L_SEQ * 128;
    float* BC = ws + off; off += (size_t)2 * L_SEQ * 32;
    float* y  = ws + off; off += (size_t)2 * L_SEQ * 128;
    float* cA = ws + off; off += (size_t)2 * NCH * 2048;
    float* cB = ws + off; off += (size_t)2 * NCH * 2048;

    k_embed<<<L_SEQ, 64, 0, stream>>>(DNA, CpG, cel, pos, Wfcc, bfcc, x0);

    float* xcur = x0;
    float* xnxt = x1;
    for (int sb = 0; sb < 8; sb++) {
        k_gemm_in<<<L_SEQ, 256, 0, stream>>>(xcur, Win, xz);
        k_conv<<<(2 * L_SEQ * DI + 255) / 256, 256, 0, stream>>>(xz, convw, convb, xc);
        k_xp_dt<<<2 * L_SEQ, 128, 0, stream>>>(xc, Wxp, Wdt, bdt, dt, BC);
        k_scan1s<<<dim3(8, NCH, 2), 256, 0, stream>>>(dt, xc, BC, Alog, cA, cB);
        k_scan3s<<<dim3(8, NCH, 2), 256, 0, stream>>>(dt, xc, BC, Alog, Dres, cA, cB, y);
        k_outln<<<L_SEQ, 64, 0, stream>>>(xcur, y, xz, Wout, lng, lnb, xnxt, (sb % 2 == 0) ? 0 : 1);
        float* tmp = xcur; xcur = xnxt; xnxt = tmp;
    }

    k_epilogue<<<1, 64, 0, stream>>>(xcur, Wfc, bfc, ytrue, halfwin, rows, (float*)d_out);
}

// Round 5
// 883.901 us; speedup vs baseline: 2.7458x; 1.1090x over previous
//
#include <hip/hip_runtime.h>
#include <hip/hip_bf16.h>
#include <math.h>

#define L_SEQ 6464
#define DM 64
#define DI 128
#define DS 16
#define CHUNK 101
#define NCH 64
#define TSTR 108   // padded LDS stride: 27*16B aligned; 12s mod 32 -> 2-way alias only (free)

// ---------------- prologue: concat + pos, then @W_fcc + b_fcc ----------------
__global__ void k_embed(const float* __restrict__ DNA, const float* __restrict__ CpG,
                        const float* __restrict__ cell, const float* __restrict__ pos,
                        const float* __restrict__ Wfcc, const float* __restrict__ bfcc,
                        float* __restrict__ x0) {
    int l = blockIdx.x;
    int j = threadIdx.x;  // 64
    __shared__ float in64[64];
    float v;
    if (j < 16)       v = CpG[l * 16 + j];
    else if (j < 32)  v = cell[l * 16 + (j - 16)];
    else              v = DNA[l * 32 + (j - 32)];
    v += pos[l * 64 + j];
    in64[j] = v;
    __syncthreads();
    float acc = bfcc[j];
    for (int i = 0; i < 64; i++) acc += in64[i] * Wfcc[i * 64 + j];
    x0[(size_t)l * 64 + j] = acc;
}

// ---------------- xz = x @ W_in : 8 rows/block, W amortized x8 ----------------
__global__ void __launch_bounds__(256) k_gemm_in(const float* __restrict__ x,
                                                 const float* __restrict__ Win,
                                                 float* __restrict__ xz) {
    __shared__ float s_x[8][64];
    int t0 = blockIdx.x * 8;
    int tid = threadIdx.x;
    for (int i = tid; i < 8 * 64; i += 256) {
        int rr = i >> 6, c = i & 63;
        s_x[rr][c] = x[(size_t)(t0 + rr) * 64 + c];
    }
    __syncthreads();
    int j = tid;  // 256 cols
    float acc[8];
    #pragma unroll
    for (int r = 0; r < 8; r++) acc[r] = 0.f;
    for (int i = 0; i < 64; i++) {
        float w = Win[i * 256 + j];
        #pragma unroll
        for (int r = 0; r < 8; r++) acc[r] = fmaf(s_x[r][i], w, acc[r]);
    }
    #pragma unroll
    for (int r = 0; r < 8; r++) xz[(size_t)(t0 + r) * 256 + j] = acc[r];
}

// ------- fused depthwise conv(+silu) both dirs + xdbl + dt/B/C, 16-row tiles -------
__global__ void __launch_bounds__(256) k_convdt(
        const float* __restrict__ xz, const float* __restrict__ convw,
        const float* __restrict__ convb, const float* __restrict__ Wxp,
        const float* __restrict__ Wdt, const float* __restrict__ bdt,
        float* __restrict__ xc, float* __restrict__ dt, float* __restrict__ BC) {
    __shared__ __align__(16) float s_xi[22][128];   // rows t0-3 .. t0+18
    __shared__ float s_xc[16][128];
    __shared__ float s_xd[16][36];
    __shared__ float s_wxp[128 * 36];
    int t0 = blockIdx.x * 16;
    int tid = threadIdx.x;
    for (int i = tid; i < 128 * 36; i += 256) s_wxp[i] = Wxp[i];
    for (int i = tid; i < 22 * 32; i += 256) {
        int rr = i >> 5, q = i & 31;
        int r = t0 - 3 + rr;
        float4 v = make_float4(0.f, 0.f, 0.f, 0.f);
        if (r >= 0 && r < L_SEQ) v = *(const float4*)&xz[(size_t)r * 256 + 4 * q];
        s_xi[rr][4 * q + 0] = v.x;
        s_xi[rr][4 * q + 1] = v.y;
        s_xi[rr][4 * q + 2] = v.z;
        s_xi[rr][4 * q + 3] = v.w;
    }
    __syncthreads();
    for (int dir = 0; dir < 2; dir++) {
        // conv + silu
        for (int i = tid; i < 16 * 128; i += 256) {
            int rr = i >> 7, d = i & 127;
            int lr = rr + 3;  // local index of central row
            float acc = convb[d];
            if (dir == 0) {
                #pragma unroll
                for (int k = 0; k < 4; k++) acc += convw[d * 4 + k] * s_xi[lr - 3 + k][d];
            } else {
                #pragma unroll
                for (int k = 0; k < 4; k++) acc += convw[d * 4 + k] * s_xi[lr + 3 - k][d];
            }
            float v = acc / (1.f + expf(-acc));
            s_xc[rr][d] = v;
            xc[((size_t)dir * L_SEQ + t0 + rr) * 128 + d] = v;
        }
        __syncthreads();
        // xdbl = xc @ W_xp (36 cols)
        for (int o = tid; o < 16 * 36; o += 256) {
            int rr = o / 36, t = o % 36;
            float acc = 0.f;
            for (int i = 0; i < 128; i++) acc += s_xc[rr][i] * s_wxp[i * 36 + t];
            s_xd[rr][t] = acc;
        }
        __syncthreads();
        // dt = softplus(xdbl[:, :4] @ W_dt + b_dt); B,C passthrough
        for (int o = tid; o < 16 * 128; o += 256) {
            int rr = o >> 7, d = o & 127;
            float pre = bdt[d];
            #pragma unroll
            for (int r = 0; r < 4; r++) pre += s_xd[rr][r] * Wdt[r * 128 + d];
            float dtv = (pre > 20.f) ? pre : log1pf(expf(pre));
            dt[((size_t)dir * L_SEQ + t0 + rr) * 128 + d] = dtv;
        }
        for (int o = tid; o < 16 * 32; o += 256) {
            int rr = o >> 5, w = o & 31;
            BC[((size_t)dir * L_SEQ + t0 + rr) * 32 + w] = s_xd[rr][4 + w];
        }
        __syncthreads();
    }
}

// ---------------- DPP 16-lane row rotate ----------------
template<int CTRL>
__device__ __forceinline__ float ror16f(float v) {
    return __int_as_float(__builtin_amdgcn_update_dpp(0, __float_as_int(v), CTRL, 0xf, 0xf, true));
}

// ---------------- scan pass 1: staged per-chunk (a_prod, h_end) ----------------
__global__ void __launch_bounds__(256) k_scan1s(
        const float* __restrict__ dt, const float* __restrict__ xc,
        const float* __restrict__ BC, const float* __restrict__ Alog,
        float* __restrict__ cA, float* __restrict__ cB) {
    __shared__ __align__(16) float s_dt[16 * TSTR];
    __shared__ __align__(16) float s_xc[16 * TSTR];
    __shared__ __align__(16) float s_B [16 * TSTR];
    int bxd = blockIdx.x;   // d-group (8)
    int c   = blockIdx.y;   // chunk (64)
    int dir = blockIdx.z;   // 2
    int tid = threadIdx.x;
    int s = tid & 15, dl = tid >> 4;
    int d0 = bxd * 16;
    const float* dtp = dt + (size_t)dir * L_SEQ * DI;
    const float* xcp = xc + (size_t)dir * L_SEQ * DI;
    const float* bcp = BC + (size_t)dir * L_SEQ * 32;
    int t0 = c * CHUNK;
    int slab0 = dir ? (L_SEQ - CHUNK - t0) : t0;   // contiguous physical row slab
    for (int i = tid; i < CHUNK * 4; i += 256) {
        int ro = i >> 2, q = i & 3;
        int row = slab0 + ro;
        int tl = dir ? (CHUNK - 1 - ro) : ro;
        float4 dv = *(const float4*)&dtp[(size_t)row * DI + d0 + 4 * q];
        float4 xv = *(const float4*)&xcp[(size_t)row * DI + d0 + 4 * q];
        float4 bv = *(const float4*)&bcp[(size_t)row * 32 + 4 * q];
        s_dt[(4 * q + 0) * TSTR + tl] = dv.x; s_dt[(4 * q + 1) * TSTR + tl] = dv.y;
        s_dt[(4 * q + 2) * TSTR + tl] = dv.z; s_dt[(4 * q + 3) * TSTR + tl] = dv.w;
        s_xc[(4 * q + 0) * TSTR + tl] = xv.x; s_xc[(4 * q + 1) * TSTR + tl] = xv.y;
        s_xc[(4 * q + 2) * TSTR + tl] = xv.z; s_xc[(4 * q + 3) * TSTR + tl] = xv.w;
        s_B [(4 * q + 0) * TSTR + tl] = bv.x; s_B [(4 * q + 1) * TSTR + tl] = bv.y;
        s_B [(4 * q + 2) * TSTR + tl] = bv.z; s_B [(4 * q + 3) * TSTR + tl] = bv.w;
    }
    __syncthreads();
    float A = -expf(Alog[d0 * 16 + tid]);
    const int tb = dl * TSTR;
    const int sbb = s * TSTR;
    float h = 0.f, ap = 1.f;
    int tl = 0;
    for (int u = 0; u < 25; u++, tl += 4) {
        float4 dq = *(const float4*)&s_dt[tb + tl];
        float4 xq = *(const float4*)&s_xc[tb + tl];
        float4 bq = *(const float4*)&s_B [sbb + tl];
        float a;
        a = __expf(dq.x * A); h = fmaf(a, h, dq.x * xq.x * bq.x); ap *= a;
        a = __expf(dq.y * A); h = fmaf(a, h, dq.y * xq.y * bq.y); ap *= a;
        a = __expf(dq.z * A); h = fmaf(a, h, dq.z * xq.z * bq.z); ap *= a;
        a = __expf(dq.w * A); h = fmaf(a, h, dq.w * xq.w * bq.w); ap *= a;
    }
    {
        float dv = s_dt[tb + 100], xv = s_xc[tb + 100], bv = s_B[sbb + 100];
        float a = __expf(dv * A); h = fmaf(a, h, dv * xv * bv); ap *= a;
    }
    size_t o = (((size_t)dir * NCH + c) << 11) + (size_t)bxd * 256 + tid;
    cA[o] = ap;
    cB[o] = h;
}

// ------- scan pass 2: lookback (stream-ordered plain loads) + replay; y via s_dt reuse -------
__global__ void __launch_bounds__(256) k_scan3s(
        const float* __restrict__ dt, const float* __restrict__ xc,
        const float* __restrict__ BC, const float* __restrict__ Alog,
        const float* __restrict__ Dres, const float* __restrict__ cA,
        const float* __restrict__ cB, float* __restrict__ y) {
    __shared__ __align__(16) float s_dt[16 * TSTR];   // becomes y in-place
    __shared__ __align__(16) float s_xc[16 * TSTR];
    __shared__ __align__(16) float s_B [16 * TSTR];
    __shared__ __align__(16) float s_C [16 * TSTR];
    int bxd = blockIdx.x;
    int c   = blockIdx.y;
    int dir = blockIdx.z;
    int tid = threadIdx.x;
    int s = tid & 15, dl = tid >> 4;
    int d0 = bxd * 16;
    const float* dtp = dt + (size_t)dir * L_SEQ * DI;
    const float* xcp = xc + (size_t)dir * L_SEQ * DI;
    const float* bcp = BC + (size_t)dir * L_SEQ * 32;
    float* yp = y + (size_t)dir * L_SEQ * DI;
    int t0 = c * CHUNK;
    int slab0 = dir ? (L_SEQ - CHUNK - t0) : t0;
    for (int i = tid; i < CHUNK * 4; i += 256) {
        int ro = i >> 2, q = i & 3;
        int row = slab0 + ro;
        int tl = dir ? (CHUNK - 1 - ro) : ro;
        float4 dv = *(const float4*)&dtp[(size_t)row * DI + d0 + 4 * q];
        float4 xv = *(const float4*)&xcp[(size_t)row * DI + d0 + 4 * q];
        float4 bv = *(const float4*)&bcp[(size_t)row * 32 + 4 * q];
        float4 cv = *(const float4*)&bcp[(size_t)row * 32 + 16 + 4 * q];
        s_dt[(4 * q + 0) * TSTR + tl] = dv.x; s_dt[(4 * q + 1) * TSTR + tl] = dv.y;
        s_dt[(4 * q + 2) * TSTR + tl] = dv.z; s_dt[(4 * q + 3) * TSTR + tl] = dv.w;
        s_xc[(4 * q + 0) * TSTR + tl] = xv.x; s_xc[(4 * q + 1) * TSTR + tl] = xv.y;
        s_xc[(4 * q + 2) * TSTR + tl] = xv.z; s_xc[(4 * q + 3) * TSTR + tl] = xv.w;
        s_B [(4 * q + 0) * TSTR + tl] = bv.x; s_B [(4 * q + 1) * TSTR + tl] = bv.y;
        s_B [(4 * q + 2) * TSTR + tl] = bv.z; s_B [(4 * q + 3) * TSTR + tl] = bv.w;
        s_C [(4 * q + 0) * TSTR + tl] = cv.x; s_C [(4 * q + 1) * TSTR + tl] = cv.y;
        s_C [(4 * q + 2) * TSTR + tl] = cv.z; s_C [(4 * q + 3) * TSTR + tl] = cv.w;
    }
    // lookback: fold predecessor carries (written by k_scan1s; stream-ordered)
    float carry = 0.f;
    int cc = 0;
    while (cc < c) {
        int n = (c - cc < 8) ? (c - cc) : 8;
        float av[8], bv[8];
        for (int j = 0; j < n; j++) {
            size_t oo = (((size_t)dir * NCH + (cc + j)) << 11) + (size_t)bxd * 256 + tid;
            av[j] = cA[oo];
            bv[j] = cB[oo];
        }
        for (int j = 0; j < n; j++) carry = fmaf(av[j], carry, bv[j]);
        cc += n;
    }
    __syncthreads();

    float A = -expf(Alog[d0 * 16 + tid]);
    float Dv = Dres[d0 + dl];
    const int tb = dl * TSTR;
    const int sbb = s * TSTR;
    float h = carry;
    int tl = 0;
    for (int u = 0; u < 25; u++, tl += 4) {
        float4 dq = *(const float4*)&s_dt[tb + tl];
        float4 xq = *(const float4*)&s_xc[tb + tl];
        float4 bq = *(const float4*)&s_B [sbb + tl];
        float4 cq = *(const float4*)&s_C [sbb + tl];
        #pragma unroll
        for (int k = 0; k < 4; k++) {
            float dv = (k == 0) ? dq.x : (k == 1) ? dq.y : (k == 2) ? dq.z : dq.w;
            float xv = (k == 0) ? xq.x : (k == 1) ? xq.y : (k == 2) ? xq.z : xq.w;
            float bv = (k == 0) ? bq.x : (k == 1) ? bq.y : (k == 2) ? bq.z : bq.w;
            float cv = (k == 0) ? cq.x : (k == 1) ? cq.y : (k == 2) ? cq.z : cq.w;
            float a = __expf(dv * A);
            h = fmaf(a, h, dv * xv * bv);
            float val = h * cv;
            val += ror16f<0x121>(val);
            val += ror16f<0x122>(val);
            val += ror16f<0x124>(val);
            val += ror16f<0x128>(val);
            if (s == 0) s_dt[tb + tl + k] = val + xv * Dv;  // in-place y (read-before-write in wave)
        }
    }
    {
        float dv = s_dt[tb + 100], xv = s_xc[tb + 100];
        float bv = s_B[sbb + 100], cv = s_C[sbb + 100];
        float a = __expf(dv * A);
        h = fmaf(a, h, dv * xv * bv);
        float val = h * cv;
        val += ror16f<0x121>(val);
        val += ror16f<0x122>(val);
        val += ror16f<0x124>(val);
        val += ror16f<0x128>(val);
        if (s == 0) s_dt[tb + 100] = val + xv * Dv;
    }
    __syncthreads();
    for (int i = tid; i < CHUNK * 4; i += 256) {
        int ro = i >> 2, q = i & 3;
        int row = slab0 + ro;
        int tl = dir ? (CHUNK - 1 - ro) : ro;
        float4 v;
        v.x = s_dt[(4 * q + 0) * TSTR + tl];
        v.y = s_dt[(4 * q + 1) * TSTR + tl];
        v.z = s_dt[(4 * q + 2) * TSTR + tl];
        v.w = s_dt[(4 * q + 3) * TSTR + tl];
        *(float4*)&yp[(size_t)row * DI + d0 + 4 * q] = v;
    }
}

// ------- out-GEMM + silu(z) gate + residual + layernorm + permute; 4 rows/block -------
__global__ void __launch_bounds__(256) k_outln(
        const float* __restrict__ x, const float* __restrict__ y,
        const float* __restrict__ xz, const float* __restrict__ Wout,
        const float* __restrict__ lng, const float* __restrict__ lnb,
        float* __restrict__ xnext, int permMode) {
    __shared__ float s_g[4][128];
    int w = threadIdx.x >> 6;        // wave id (row within block)
    int j = threadIdx.x & 63;
    int l = blockIdx.x * 4 + w;
    float z1 = xz[(size_t)l * 256 + 128 + j];
    float z2 = xz[(size_t)l * 256 + 192 + j];
    float sz1 = z1 / (1.f + expf(-z1));
    float sz2 = z2 / (1.f + expf(-z2));
    s_g[w][j]      = 0.5f * (y[(size_t)l * 128 + j] + y[(size_t)(L_SEQ + l) * 128 + j]) * sz1;
    s_g[w][j + 64] = 0.5f * (y[(size_t)l * 128 + 64 + j] + y[(size_t)(L_SEQ + l) * 128 + 64 + j]) * sz2;
    __syncthreads();
    float acc = x[(size_t)l * 64 + j];
    for (int i = 0; i < 128; i++) acc += s_g[w][i] * Wout[i * 64 + j];
    float m = acc;
    for (int o = 32; o >= 1; o >>= 1) m += __shfl_xor(m, o);
    m *= (1.f / 64.f);
    float dv = acc - m;
    float v = dv * dv;
    for (int o = 32; o >= 1; o >>= 1) v += __shfl_xor(v, o);
    v *= (1.f / 64.f);
    float out = dv * rsqrtf(v + 1e-5f) * lng[j] + lnb[j];
    int l2;
    if (permMode == 0) l2 = (l % 64) * 101 + (l / 64);   // (s,c)->(c,s)
    else               l2 = (l % 101) * 64 + (l / 101);  // (c,s)->(s,c)
    xnext[(size_t)l2 * 64 + j] = out;
}

// ---------------- epilogue ----------------
__global__ void k_epilogue(const float* __restrict__ x, const float* __restrict__ Wfc,
                           const float* __restrict__ bfc, const float* __restrict__ ytrue,
                           const int* __restrict__ halfwin, const int* __restrict__ rows,
                           float* __restrict__ out) {
    int k = threadIdx.x;  // 64
    int hw = halfwin[0];
    int c = rows[k];
    const float* xr = x + ((size_t)hw * 64 + c) * 64;
    float acc = bfc[0];
    for (int i = 0; i < 64; i++) acc += xr[i] * Wfc[i];
    float s = 1.f / (1.f + expf(-acc));
    float r = 1.f - fabsf(ytrue[k] - s);
    out[k] = r;
}

extern "C" void kernel_launch(void* const* d_in, const int* in_sizes, int n_in,
                              void* d_out, int out_size, void* d_ws, size_t ws_size,
                              hipStream_t stream) {
    const float* DNA   = (const float*)d_in[0];
    const float* CpG   = (const float*)d_in[1];
    const float* cel   = (const float*)d_in[2];
    const float* pos   = (const float*)d_in[3];
    const float* ytrue = (const float*)d_in[4];
    const float* Wfcc  = (const float*)d_in[5];
    const float* bfcc  = (const float*)d_in[6];
    const float* Win   = (const float*)d_in[7];
    const float* convw = (const float*)d_in[8];
    const float* convb = (const float*)d_in[9];
    const float* Wxp   = (const float*)d_in[10];
    const float* Wdt   = (const float*)d_in[11];
    const float* bdt   = (const float*)d_in[12];
    const float* Alog  = (const float*)d_in[13];
    const float* Dres  = (const float*)d_in[14];
    const float* Wout  = (const float*)d_in[15];
    const float* lng   = (const float*)d_in[16];
    const float* lnb   = (const float*)d_in[17];
    const float* Wfc   = (const float*)d_in[18];
    const float* bfc   = (const float*)d_in[19];
    const int* halfwin = (const int*)d_in[20];
    const int* rows    = (const int*)d_in[21];

    float* ws = (float*)d_ws;
    size_t off = 0;
    float* x0 = ws + off; off += (size_t)L_SEQ * 64;
    float* x1 = ws + off; off += (size_t)L_SEQ * 64;
    float* xz = ws + off; off += (size_t)L_SEQ * 256;
    float* xc = ws + off; off += (size_t)2 * L_SEQ * 128;
    float* dt = ws + off; off += (size_t)2 * L_SEQ * 128;
    float* BC = ws + off; off += (size_t)2 * L_SEQ * 32;
    float* y  = ws + off; off += (size_t)2 * L_SEQ * 128;
    float* cA = ws + off; off += (size_t)2 * NCH * 2048;
    float* cB = ws + off; off += (size_t)2 * NCH * 2048;

    k_embed<<<L_SEQ, 64, 0, stream>>>(DNA, CpG, cel, pos, Wfcc, bfcc, x0);

    float* xcur = x0;
    float* xnxt = x1;
    for (int sb = 0; sb < 8; sb++) {
        k_gemm_in<<<L_SEQ / 8, 256, 0, stream>>>(xcur, Win, xz);
        k_convdt<<<L_SEQ / 16, 256, 0, stream>>>(xz, convw, convb, Wxp, Wdt, bdt, xc, dt, BC);
        k_scan1s<<<dim3(8, NCH, 2), 256, 0, stream>>>(dt, xc, BC, Alog, cA, cB);
        k_scan3s<<<dim3(8, NCH, 2), 256, 0, stream>>>(dt, xc, BC, Alog, Dres, cA, cB, y);
        k_outln<<<L_SEQ / 4, 256, 0, stream>>>(xcur, y, xz, Wout, lng, lnb, xnxt, (sb % 2 == 0) ? 0 : 1);
        float* tmp = xcur; xcur = xnxt; xnxt = tmp;
    }

    k_epilogue<<<1, 64, 0, stream>>>(xcur, Wfc, bfc, ytrue, halfwin, rows, (float*)d_out);
}